// Round 4
// baseline (728.386 us; speedup 1.0000x reference)
//
#include <hip/hip_runtime.h>
#include <math.h>

#define BATCH 512
#define SEQ   200
#define TOK   10
#define EMB   25
#define HID   64
#define G3    192   // 3*HID
#define CH    20    // gru xp-staging chunk (SEQ % CH == 0)
#define NC    (SEQ / CH)

__device__ __forceinline__ float fast_sigmoid(float t) {
    float e = __expf(-t);
    return __builtin_amdgcn_rcpf(1.f + e);
}
__device__ __forceinline__ float fast_tanh(float t) {
    float e2 = __expf(2.f * t);
    return 1.f - 2.f * __builtin_amdgcn_rcpf(e2 + 1.f);
}

// ---------------------------------------------------------------------------
// Kernel 1: fused embedding-bag mean + input projection (both directions).
// One wave per (b,s) position, grid-stride. Lane l holds W columns
// {l, 64+l, 128+l} of W_f and W_b in registers (150 VGPRs).
// __launch_bounds__(256, 1): VGPR cap 512 so the weights DO NOT SPILL
// (R3 regression: (256,2) capped at 128 VGPRs -> scratch spill -> 280us).
// Writes dir-split xp_f[pos][192], xp_b[pos][192].
// ---------------------------------------------------------------------------
__global__ __launch_bounds__(256, 1) void emb_xproj_kernel(
    const int* __restrict__ ids_g, const float* __restrict__ emb,
    const float* __restrict__ W_f, const float* __restrict__ b_f,
    const float* __restrict__ W_b, const float* __restrict__ b_b,
    float* __restrict__ xpf, float* __restrict__ xpb,
    float* __restrict__ mask)
{
    const int lane = threadIdx.x & 63;
    const int wave = threadIdx.x >> 6;

    float Wreg[EMB][6];
    float bl[6];
    #pragma unroll
    for (int g = 0; g < 3; g++) {
        #pragma unroll
        for (int e = 0; e < EMB; e++) {
            Wreg[e][g]     = W_f[e * G3 + g * 64 + lane];
            Wreg[e][g + 3] = W_b[e * G3 + g * 64 + lane];
        }
        bl[g]     = b_f[g * 64 + lane];
        bl[g + 3] = b_b[g * 64 + lane];
    }

    for (int pos = blockIdx.x * 4 + wave; pos < BATCH * SEQ; pos += gridDim.x * 4) {
        const int* ids = ids_g + (size_t)pos * TOK;
        float acc = 0.f;
        int cnt = 0;
        #pragma unroll
        for (int t = 0; t < TOK; t++) {
            int id = ids[t];
            if (id != 0) {
                cnt++;
                if (lane < EMB) acc += emb[(size_t)id * EMB + lane];
            }
        }
        float xv = cnt ? acc / (float)cnt : 0.f;
        if (lane == 0) mask[pos] = (ids[0] != 0) ? 1.f : 0.f;

        float xr[EMB];
        #pragma unroll
        for (int e = 0; e < EMB; e++) xr[e] = __shfl(xv, e);

        float* of = xpf + (size_t)pos * G3;
        float* ob = xpb + (size_t)pos * G3;
        #pragma unroll
        for (int g = 0; g < 6; g++) {
            float a0 = bl[g], a1 = 0.f;
            #pragma unroll
            for (int e = 0; e < 24; e += 2) {
                a0 = fmaf(xr[e + 0], Wreg[e + 0][g], a0);
                a1 = fmaf(xr[e + 1], Wreg[e + 1][g], a1);
            }
            a0 = fmaf(xr[24], Wreg[24][g], a0);
            float v = a0 + a1;
            if (g < 3) of[g * 64 + lane] = v;
            else       ob[(g - 3) * 64 + lane] = v;
        }
    }
}

// ---------------------------------------------------------------------------
// Kernel 2: GRU scan — one wave per (batch, direction), 64 threads.
// Lane j holds the three recurrent columns Uz/Ur/Uh (192 VGPRs).
// xp arrives via chunked staging: every CH=20 steps, 15 float4/lane are
// burst-loaded into registers for the NEXT chunk (≈10k cycles of lookahead,
// fully hiding HBM/L3 latency), then ds_written to the alternate LDS buffer
// after the current chunk's compute. In-loop xp access = 3 conflict-free
// ds_read_b32. Single wave, in-order DS pipe: no barriers anywhere.
// ---------------------------------------------------------------------------
__global__ __launch_bounds__(64, 1) void gru_kernel(
    const float* __restrict__ xpf, const float* __restrict__ xpb,
    const float* __restrict__ maskg,
    const float* __restrict__ U_f, const float* __restrict__ b_f,
    const float* __restrict__ U_b, const float* __restrict__ b_b,
    float* __restrict__ outg, float* __restrict__ hT)
{
    const int bidx = blockIdx.x;
    const int dir  = bidx >> 9;        // 0 = forward, 1 = backward
    const int b    = bidx & 511;
    const int j    = threadIdx.x;      // 0..63

    const float* U    = dir ? U_b : U_f;
    const float* bias = dir ? b_b : b_f;
    const float* xp_d = (dir ? xpb : xpf) + (size_t)b * SEQ * G3;

    float Uz[HID], Ur[HID], Uh[HID];
    #pragma unroll
    for (int k = 0; k < HID; k++) {
        Uz[k] = U[k * G3 + j];
        Ur[k] = U[k * G3 + HID + j];
        Uh[k] = U[k * G3 + 2 * HID + j];
    }
    const float bzr = bias[G3 + j];
    const float brr = bias[G3 + HID + j];
    const float bhr = bias[G3 + 2 * HID + j];

    __shared__ float ms[SEQ];
    __shared__ __align__(16) float hs[HID];
    __shared__ __align__(16) float xs[2][CH * G3];   // 2 x 15 KB

    for (int i = j; i < SEQ; i += 64) ms[i] = maskg[(size_t)b * SEQ + i];
    hs[j] = 0.f;
    __syncthreads();   // once (single wave)

    float4 pre[15];
    // slab for chunk starting at local step t0 covers CH contiguous source
    // rows; for dir=1 they are the rows SEQ-t0-CH .. SEQ-t0-1.
    #define LOAD_SLAB(t0)                                                     \
        {   const int r0 = dir ? (SEQ - (t0) - CH) : (t0);                    \
            const float4* s4 = (const float4*)(xp_d + (size_t)r0 * G3);       \
            _Pragma("unroll")                                                 \
            for (int w = 0; w < 15; w++) pre[w] = s4[w * 64 + j];             \
        }
    #define WRITE_SLAB(buf)                                                   \
        {   float4* d4 = (float4*)xs[buf];                                    \
            _Pragma("unroll")                                                 \
            for (int w = 0; w < 15; w++) d4[w * 64 + j] = pre[w];             \
        }

    LOAD_SLAB(0);
    WRITE_SLAB(0);

    float h = 0.f;
    float* orow_base = outg + (size_t)b * SEQ * (2 * HID) + dir * HID + j;
    const float4* hs4 = (const float4*)hs;

    for (int c = 0; c < NC; c++) {
        if (c + 1 < NC) LOAD_SLAB((c + 1) * CH);   // fire loads; use later

        const float* xbuf = xs[c & 1];
        #pragma unroll 4
        for (int i = 0; i < CH; i++) {
            const int t  = c * CH + i;
            const int s  = dir ? (SEQ - 1 - t) : t;
            const int li = dir ? (CH - 1 - i) : i;
            const float* xr = xbuf + li * G3 + j;
            const float cz = xr[0], cr = xr[64], chv = xr[128];

            float az0 = bzr, az1 = 0.f, ar0 = brr, ar1 = 0.f, ah0 = bhr, ah1 = 0.f;
            #pragma unroll
            for (int k4 = 0; k4 < HID / 4; k4++) {
                float4 hv = hs4[k4];
                int k = k4 * 4;
                az0 = fmaf(hv.x, Uz[k],     az0); az1 = fmaf(hv.y, Uz[k + 1], az1);
                az0 = fmaf(hv.z, Uz[k + 2], az0); az1 = fmaf(hv.w, Uz[k + 3], az1);
                ar0 = fmaf(hv.x, Ur[k],     ar0); ar1 = fmaf(hv.y, Ur[k + 1], ar1);
                ar0 = fmaf(hv.z, Ur[k + 2], ar0); ar1 = fmaf(hv.w, Ur[k + 3], ar1);
                ah0 = fmaf(hv.x, Uh[k],     ah0); ah1 = fmaf(hv.y, Uh[k + 1], ah1);
                ah0 = fmaf(hv.z, Uh[k + 2], ah0); ah1 = fmaf(hv.w, Uh[k + 3], ah1);
            }

            float z  = fast_sigmoid(cz + az0 + az1);
            float r  = fast_sigmoid(cr + ar0 + ar1);
            float hh = fast_tanh(chv + r * (ah0 + ah1));
            float hn = z * h + (1.f - z) * hh;
            hn = (ms[s] != 0.f) ? hn : h;
            h = hn;

            __builtin_amdgcn_wave_barrier();
            hs[j] = hn;
            __builtin_amdgcn_wave_barrier();

            orow_base[(size_t)s * (2 * HID)] = hn;   // fire-and-forget
        }

        if (c + 1 < NC) WRITE_SLAB((c + 1) & 1);   // loads done long ago
    }
    if (dir == 0) hT[(size_t)b * HID + j] = h;
    #undef LOAD_SLAB
    #undef WRITE_SLAB
}

// ---------------------------------------------------------------------------
// Kernel 3: attention pooling. One block (256 threads = 4 waves) per batch.
// ---------------------------------------------------------------------------
__global__ __launch_bounds__(256) void attn_kernel(
    const float* __restrict__ outg, const float* __restrict__ maskg,
    const float* __restrict__ hT,
    const float* __restrict__ W_k, const float* __restrict__ b_k,
    const float* __restrict__ W_q, const float* __restrict__ b_q,
    const float* __restrict__ W_e, const float* __restrict__ b_e,
    float* __restrict__ ctx)
{
    const int b   = blockIdx.x;
    const int tid = threadIdx.x;

    __shared__ float Wks[2 * HID * HID];   // 128x64 = 32 KB
    __shared__ float qs[HID];
    __shared__ float es[SEQ];
    __shared__ float part[2 * HID];

    for (int i = tid; i < 2 * HID * HID; i += 256) Wks[i] = W_k[i];
    if (tid < HID) {
        float q = b_q[tid];
        const float* hrow = hT + (size_t)b * HID;
        #pragma unroll 8
        for (int i = 0; i < HID; i++) q = fmaf(hrow[i], W_q[i * HID + tid], q);
        qs[tid] = q;
    }
    __syncthreads();

    const int wave = tid >> 6;
    const int lane = tid & 63;
    const float bk = b_k[lane];
    const float we = W_e[lane];
    const float be = b_e[0];

    for (int s = wave; s < SEQ; s += 4) {
        const float4* orow4 = (const float4*)(outg + ((size_t)b * SEQ + s) * (2 * HID));
        float a0 = 0.f, a1 = 0.f, a2 = 0.f, a3 = 0.f;
        #pragma unroll
        for (int i4 = 0; i4 < (2 * HID) / 4; i4++) {
            float4 ov = orow4[i4];
            int i = i4 * 4;
            a0 = fmaf(ov.x, Wks[(i + 0) * HID + lane], a0);
            a1 = fmaf(ov.y, Wks[(i + 1) * HID + lane], a1);
            a2 = fmaf(ov.z, Wks[(i + 2) * HID + lane], a2);
            a3 = fmaf(ov.w, Wks[(i + 3) * HID + lane], a3);
        }
        float t = tanhf(((a0 + a1) + (a2 + a3)) + bk + qs[lane]) * we;
        #pragma unroll
        for (int off = 32; off > 0; off >>= 1) t += __shfl_down(t, off);
        if (lane == 0) {
            float pen = (maskg[(size_t)b * SEQ + s] != 0.f) ? 0.f : -1e9f;
            es[s] = t + be + pen;
        }
    }
    __syncthreads();

    if (tid < 64) {
        float mx = -1e30f;
        for (int s2 = tid; s2 < SEQ; s2 += 64) mx = fmaxf(mx, es[s2]);
        #pragma unroll
        for (int off = 32; off > 0; off >>= 1) mx = fmaxf(mx, __shfl_xor(mx, off));
        float sum = 0.f;
        for (int s2 = tid; s2 < SEQ; s2 += 64) {
            float w = expf(es[s2] - mx);
            es[s2] = w;
            sum += w;
        }
        #pragma unroll
        for (int off = 32; off > 0; off >>= 1) sum += __shfl_xor(sum, off);
        float inv = 1.f / sum;
        for (int s2 = tid; s2 < SEQ; s2 += 64) es[s2] *= inv;
    }
    __syncthreads();

    {
        const int half = tid >> 7;          // 0 or 1
        const int jj   = tid & 127;
        float a = 0.f;
        for (int s2 = half; s2 < SEQ; s2 += 2)
            a = fmaf(es[s2], outg[((size_t)b * SEQ + s2) * (2 * HID) + jj], a);
        if (half == 1) part[jj] = a;
        __syncthreads();
        if (half == 0)
            ctx[(size_t)b * (2 * HID) + jj] = a + part[jj];
    }
}

// ---------------------------------------------------------------------------
extern "C" void kernel_launch(void* const* d_in, const int* in_sizes, int n_in,
                              void* d_out, int out_size, void* d_ws, size_t ws_size,
                              hipStream_t stream) {
    const int*   ids = (const int*)  d_in[0];
    const float* emb = (const float*)d_in[1];
    const float* W_f = (const float*)d_in[2];
    const float* U_f = (const float*)d_in[3];
    const float* b_f = (const float*)d_in[4];
    const float* W_b = (const float*)d_in[5];
    const float* U_b = (const float*)d_in[6];
    const float* b_b = (const float*)d_in[7];
    const float* W_k = (const float*)d_in[8];
    const float* b_k = (const float*)d_in[9];
    const float* W_q = (const float*)d_in[10];
    const float* b_q = (const float*)d_in[11];
    const float* W_e = (const float*)d_in[12];
    const float* b_e = (const float*)d_in[13];

    float* ws   = (float*)d_ws;
    // workspace layout (floats):
    //   xp_f : [0, 19'660'800)                (B*S*192)
    //   xp_b : [19'660'800, 39'321'600)       (B*S*192)
    //   mask : [39'321'600, 39'424'000)       (B*S)
    //   out  : [39'424'000, 52'531'200)       (B*S*2H)
    //   hT   : [52'531'200, 52'563'968)       (B*H)
    float* xpf  = ws;
    float* xpb  = ws + 19660800;
    float* mask = ws + 39321600;
    float* out  = ws + 39424000;
    float* hT   = ws + 52531200;

    emb_xproj_kernel<<<1280, 256, 0, stream>>>(ids, emb, W_f, b_f, W_b, b_b,
                                               xpf, xpb, mask);
    gru_kernel<<<1024, 64, 0, stream>>>(xpf, xpb, mask, U_f, b_f, U_b, b_b,
                                        out, hT);
    attn_kernel<<<BATCH, 256, 0, stream>>>(out, mask, hT, W_k, b_k,
                                           W_q, b_q, W_e, b_e, (float*)d_out);
}

// Round 5
// 713.630 us; speedup vs baseline: 1.0207x; 1.0207x over previous
//
#include <hip/hip_runtime.h>
#include <math.h>

#define BATCH 512
#define SEQ   200
#define TOK   10
#define EMB   25
#define HID   64
#define G3    192   // 3*HID
#define CH    20    // gru xp-staging chunk (SEQ % CH == 0)
#define NC    (SEQ / CH)
#define VOC   50000
#define EPAD  28    // padded emb row -> 112 B, 16B-aligned
#define WTP   32    // padded Wt row (128 B, s_load friendly)

__device__ __forceinline__ float fast_sigmoid(float t) {
    float e = __expf(-t);
    return __builtin_amdgcn_rcpf(1.f + e);
}
__device__ __forceinline__ float fast_tanh(float t) {
    float e2 = __expf(2.f * t);
    return 1.f - 2.f * __builtin_amdgcn_rcpf(e2 + 1.f);
}

typedef const __attribute__((address_space(1))) unsigned int* as1_u32p;
typedef __attribute__((address_space(3))) unsigned int* as3_u32p;

// async global->LDS, 16B/lane. lds base must be wave-uniform; HW adds lane*16.
__device__ __forceinline__ void gload_lds16(const float* g, float* lds_uniform) {
#if __has_builtin(__builtin_amdgcn_global_load_lds)
    __builtin_amdgcn_global_load_lds((as1_u32p)g, (as3_u32p)lds_uniform, 16, 0, 0);
#else
    ((float4*)lds_uniform)[threadIdx.x & 63] = *(const float4*)g;
#endif
}

// ---------------------------------------------------------------------------
// Prep 1: pad embedding table to 28-float rows (16B-aligned gather rows)
// ---------------------------------------------------------------------------
__global__ __launch_bounds__(256) void pad_emb_kernel(
    const float* __restrict__ emb, float* __restrict__ embp)
{
    const int total = VOC * EPAD;
    for (int idx = blockIdx.x * 256 + threadIdx.x; idx < total; idx += gridDim.x * 256) {
        int r = idx / EPAD;
        int e = idx - r * EPAD;
        embp[idx] = (e < EMB) ? emb[r * EMB + e] : 0.f;
    }
}

// ---------------------------------------------------------------------------
// Prep 2: Wt[384][32] = transposed [W_f|W_b] columns (+input bias at [25]);
//         Wkt[64][128] = transposed W_k.
// ---------------------------------------------------------------------------
__global__ __launch_bounds__(512) void prep_w_kernel(
    const float* __restrict__ W_f, const float* __restrict__ b_f,
    const float* __restrict__ W_b, const float* __restrict__ b_b,
    const float* __restrict__ W_k,
    float* __restrict__ Wt, float* __restrict__ Wkt)
{
    const int t = threadIdx.x;
    if (t < 2 * G3) {
        const float* W  = (t < G3) ? W_f : W_b;
        const float* bb = (t < G3) ? b_f : b_b;
        const int c = (t < G3) ? t : t - G3;
        float* row = Wt + t * WTP;
        for (int e = 0; e < EMB; e++) row[e] = W[e * G3 + c];
        row[25] = bb[c];
        for (int e = 26; e < WTP; e++) row[e] = 0.f;
    }
    for (int i = t; i < 2 * HID * HID; i += 512) {
        int r = i >> 7, col = i & 127;
        Wkt[i] = W_k[col * HID + r];     // Wkt[r][col] = W_k[col][r]
    }
}

// ---------------------------------------------------------------------------
// Kernel 1 v3: fused embedding-bag mean + input projection, POSITION-PER-LANE.
// Lane = one (b,s) position: x[25] per-lane registers; weights are the
// wave-uniform operand (uniform-address loads of Wt rows -> s_load + SGPR
// FMA operand). Nothing big to sink. 16 cols/chunk -> lane writes 64 B
// contiguous per chunk (full HBM granule).
// ---------------------------------------------------------------------------
__global__ __launch_bounds__(64) void emb_xproj_kernel(
    const int* __restrict__ ids_g, const float* __restrict__ embp,
    const float* __restrict__ Wt,
    float* __restrict__ xpf, float* __restrict__ xpb, float* __restrict__ mask)
{
    const int lane = threadIdx.x;
    const int pos  = blockIdx.x * 64 + lane;    // grid 1600 x 64 covers 102400
    const int* ids = ids_g + (size_t)pos * TOK;

    float4 a4[7];
    #pragma unroll
    for (int q = 0; q < 7; q++) a4[q] = make_float4(0.f, 0.f, 0.f, 0.f);
    int cnt = 0;
    int id0 = ids[0];
    #pragma unroll
    for (int t = 0; t < TOK; t++) {
        int id = ids[t];
        float sel = (id != 0) ? 1.f : 0.f;
        cnt += (id != 0) ? 1 : 0;
        const float4* row = (const float4*)(embp + (size_t)id * EPAD);
        #pragma unroll
        for (int q = 0; q < 7; q++) {
            float4 v = row[q];
            a4[q].x = fmaf(sel, v.x, a4[q].x);
            a4[q].y = fmaf(sel, v.y, a4[q].y);
            a4[q].z = fmaf(sel, v.z, a4[q].z);
            a4[q].w = fmaf(sel, v.w, a4[q].w);
        }
    }
    mask[pos] = (id0 != 0) ? 1.f : 0.f;
    const float invd = cnt ? (1.f / (float)cnt) : 0.f;

    float xx[EMB];
    #pragma unroll
    for (int q = 0; q < 7; q++) {
        if (4 * q + 0 < EMB) xx[4 * q + 0] = a4[q].x * invd;
        if (4 * q + 1 < EMB) xx[4 * q + 1] = a4[q].y * invd;
        if (4 * q + 2 < EMB) xx[4 * q + 2] = a4[q].z * invd;
        if (4 * q + 3 < EMB) xx[4 * q + 3] = a4[q].w * invd;
    }

    float* const rowf = xpf + (size_t)pos * G3;
    float* const rowb = xpb + (size_t)pos * G3;
    for (int chunk = 0; chunk < 24; chunk++) {   // 16 cols each
        float acc[16];
        const float* wbase = Wt + chunk * 16 * WTP;   // wave-uniform
        #pragma unroll
        for (int cc = 0; cc < 16; cc++) {
            const float* wrow = wbase + cc * WTP;
            float a = wrow[25];                       // input bias
            #pragma unroll
            for (int e = 0; e < EMB; e++) a = fmaf(xx[e], wrow[e], a);
            acc[cc] = a;
        }
        float* dst = (chunk < 12) ? (rowf + chunk * 16) : (rowb + (chunk - 12) * 16);
        float4* d4 = (float4*)dst;
        d4[0] = make_float4(acc[0],  acc[1],  acc[2],  acc[3]);
        d4[1] = make_float4(acc[4],  acc[5],  acc[6],  acc[7]);
        d4[2] = make_float4(acc[8],  acc[9],  acc[10], acc[11]);
        d4[3] = make_float4(acc[12], acc[13], acc[14], acc[15]);
    }
}

// ---------------------------------------------------------------------------
// Kernel 2 v5: GRU scan — one wave per (batch, direction).
// Uz/Ur/Uh per-lane registers (192 VGPRs). xp staged per CH=20 steps via
// async global_load_lds (zero VGPR cost -> no sinking; total demand ~232).
// Explicit s_waitcnt vmcnt(0) at chunk boundaries; no barriers in the loop.
// ---------------------------------------------------------------------------
__global__ __launch_bounds__(64, 1) void gru_kernel(
    const float* __restrict__ xpf, const float* __restrict__ xpb,
    const float* __restrict__ maskg,
    const float* __restrict__ U_f, const float* __restrict__ b_f,
    const float* __restrict__ U_b, const float* __restrict__ b_b,
    float* __restrict__ outg, float* __restrict__ hT)
{
    const int bidx = blockIdx.x;
    const int dir  = bidx >> 9;
    const int b    = bidx & 511;
    const int j    = threadIdx.x;

    const float* U    = dir ? U_b : U_f;
    const float* bias = dir ? b_b : b_f;
    const float* xp_d = (dir ? xpb : xpf) + (size_t)b * SEQ * G3;

    float Uz[HID], Ur[HID], Uh[HID];
    #pragma unroll
    for (int k = 0; k < HID; k++) {
        Uz[k] = U[k * G3 + j];
        Ur[k] = U[k * G3 + HID + j];
        Uh[k] = U[k * G3 + 2 * HID + j];
    }
    const float bzr = bias[G3 + j];
    const float brr = bias[G3 + HID + j];
    const float bhr = bias[G3 + 2 * HID + j];

    __shared__ float ms[SEQ];
    __shared__ __align__(16) float hs[HID];
    __shared__ __align__(16) float xs[2][CH * G3];   // 2 x 15 KB

    for (int i = j; i < SEQ; i += 64) ms[i] = maskg[(size_t)b * SEQ + i];
    hs[j] = 0.f;
    __syncthreads();

    // issue chunk-0 staging: 15 instrs x (64 lanes x 16 B) = 15 KB
    {
        const int r0 = dir ? (SEQ - CH) : 0;
        const float* src = xp_d + (size_t)r0 * G3;
        #pragma unroll
        for (int w = 0; w < 15; w++)
            gload_lds16(src + w * 256 + j * 4, &xs[0][w * 256]);
    }

    float h = 0.f;
    float* obase = outg + (size_t)b * SEQ * (2 * HID) + dir * HID + j;
    const float4* hs4 = (const float4*)hs;

    for (int c = 0; c < NC; c++) {
        __builtin_amdgcn_s_waitcnt(0x0f70);   // vmcnt(0): chunk data landed
        __builtin_amdgcn_wave_barrier();
        if (c + 1 < NC) {                     // prefetch next chunk (async)
            const int t0 = (c + 1) * CH;
            const int r0 = dir ? (SEQ - t0 - CH) : t0;
            const float* src = xp_d + (size_t)r0 * G3;
            float* dstb = xs[(c + 1) & 1];
            #pragma unroll
            for (int w = 0; w < 15; w++)
                gload_lds16(src + w * 256 + j * 4, &dstb[w * 256]);
        }

        const float* xbuf = xs[c & 1];
        for (int i = 0; i < CH; i++) {
            const int t  = c * CH + i;
            const int s  = dir ? (SEQ - 1 - t) : t;
            const int li = dir ? (CH - 1 - i) : i;
            const float* xr = xbuf + li * G3 + j;
            const float cz = xr[0], cr = xr[64], chv = xr[128];

            float az0 = bzr, az1 = 0.f, ar0 = brr, ar1 = 0.f, ah0 = bhr, ah1 = 0.f;
            #pragma unroll
            for (int k4 = 0; k4 < HID / 4; k4++) {
                float4 hv = hs4[k4];
                int k = k4 * 4;
                az0 = fmaf(hv.x, Uz[k],     az0); az1 = fmaf(hv.y, Uz[k + 1], az1);
                az0 = fmaf(hv.z, Uz[k + 2], az0); az1 = fmaf(hv.w, Uz[k + 3], az1);
                ar0 = fmaf(hv.x, Ur[k],     ar0); ar1 = fmaf(hv.y, Ur[k + 1], ar1);
                ar0 = fmaf(hv.z, Ur[k + 2], ar0); ar1 = fmaf(hv.w, Ur[k + 3], ar1);
                ah0 = fmaf(hv.x, Uh[k],     ah0); ah1 = fmaf(hv.y, Uh[k + 1], ah1);
                ah0 = fmaf(hv.z, Uh[k + 2], ah0); ah1 = fmaf(hv.w, Uh[k + 3], ah1);
            }

            float z  = fast_sigmoid(cz + az0 + az1);
            float r  = fast_sigmoid(cr + ar0 + ar1);
            float hh = fast_tanh(chv + r * (ah0 + ah1));
            float hn = z * h + (1.f - z) * hh;
            hn = (ms[s] != 0.f) ? hn : h;
            h = hn;

            __builtin_amdgcn_wave_barrier();
            hs[j] = hn;
            __builtin_amdgcn_wave_barrier();

            obase[(size_t)s * (2 * HID)] = hn;   // fire-and-forget
        }
    }
    if (dir == 0) hT[(size_t)b * HID + j] = h;
}

// ---------------------------------------------------------------------------
// Kernel 3 v3: attention, POSITION-PER-LANE scores. Lane = seq position s
// (wave w covers s = w*50 + lane, lane<50). Out-row in 32 float4 registers;
// W_k columns read wave-uniform from Wkt (s_load); score fully per-lane.
// ---------------------------------------------------------------------------
__global__ __launch_bounds__(256, 2) void attn_kernel(
    const float* __restrict__ outg, const float* __restrict__ maskg,
    const float* __restrict__ hT, const float* __restrict__ Wkt,
    const float* __restrict__ b_k, const float* __restrict__ W_q,
    const float* __restrict__ b_q, const float* __restrict__ W_e,
    const float* __restrict__ b_e, float* __restrict__ ctx)
{
    const int b   = blockIdx.x;
    const int tid = threadIdx.x;

    __shared__ float qs[HID];
    __shared__ float es[SEQ];
    __shared__ float part[2 * HID];

    if (tid < HID) {
        float q = b_q[tid];
        const float* hrow = hT + (size_t)b * HID;
        #pragma unroll 8
        for (int i = 0; i < HID; i++) q = fmaf(hrow[i], W_q[i * HID + tid], q);
        qs[tid] = q;
    }
    __syncthreads();

    const int wave = tid >> 6;
    const int lane = tid & 63;
    const int s    = wave * 50 + lane;    // 4 waves x 50 = 200
    if (lane < 50) {
        const float4* orow = (const float4*)(outg + ((size_t)b * SEQ + s) * (2 * HID));
        float4 o[32];
        #pragma unroll
        for (int q = 0; q < 32; q++) o[q] = orow[q];

        float e_acc = 0.f;
        for (int c = 0; c < HID; c++) {
            const float* wr = Wkt + c * 128;      // wave-uniform row
            float k = b_k[c];
            #pragma unroll
            for (int q = 0; q < 32; q++) {
                k = fmaf(o[q].x, wr[4 * q + 0], k);
                k = fmaf(o[q].y, wr[4 * q + 1], k);
                k = fmaf(o[q].z, wr[4 * q + 2], k);
                k = fmaf(o[q].w, wr[4 * q + 3], k);
            }
            e_acc = fmaf(W_e[c], fast_tanh(k + qs[c]), e_acc);
        }
        float pen = (maskg[(size_t)b * SEQ + s] != 0.f) ? 0.f : -1e9f;
        es[s] = e_acc + b_e[0] + pen;
    }
    __syncthreads();

    if (tid < 64) {
        float mx = -1e30f;
        for (int s2 = tid; s2 < SEQ; s2 += 64) mx = fmaxf(mx, es[s2]);
        #pragma unroll
        for (int off = 32; off > 0; off >>= 1) mx = fmaxf(mx, __shfl_xor(mx, off));
        float sum = 0.f;
        for (int s2 = tid; s2 < SEQ; s2 += 64) {
            float w = expf(es[s2] - mx);
            es[s2] = w;
            sum += w;
        }
        #pragma unroll
        for (int off = 32; off > 0; off >>= 1) sum += __shfl_xor(sum, off);
        float inv = 1.f / sum;
        for (int s2 = tid; s2 < SEQ; s2 += 64) es[s2] *= inv;
    }
    __syncthreads();

    {
        const int half = tid >> 7;
        const int jj   = tid & 127;
        float a = 0.f;
        for (int s2 = half; s2 < SEQ; s2 += 2)
            a = fmaf(es[s2], outg[((size_t)b * SEQ + s2) * (2 * HID) + jj], a);
        if (half == 1) part[jj] = a;
        __syncthreads();
        if (half == 0)
            ctx[(size_t)b * (2 * HID) + jj] = a + part[jj];
    }
}

// ---------------------------------------------------------------------------
extern "C" void kernel_launch(void* const* d_in, const int* in_sizes, int n_in,
                              void* d_out, int out_size, void* d_ws, size_t ws_size,
                              hipStream_t stream) {
    const int*   ids = (const int*)  d_in[0];
    const float* emb = (const float*)d_in[1];
    const float* W_f = (const float*)d_in[2];
    const float* U_f = (const float*)d_in[3];
    const float* b_f = (const float*)d_in[4];
    const float* W_b = (const float*)d_in[5];
    const float* U_b = (const float*)d_in[6];
    const float* b_b = (const float*)d_in[7];
    const float* W_k = (const float*)d_in[8];
    const float* b_k = (const float*)d_in[9];
    const float* W_q = (const float*)d_in[10];
    const float* b_q = (const float*)d_in[11];
    const float* W_e = (const float*)d_in[12];
    const float* b_e = (const float*)d_in[13];

    float* ws = (float*)d_ws;
    // workspace layout (floats):
    //   xpf  : [0, 19'660'800)
    //   xpb  : [19'660'800, 39'321'600)
    //   mask : [39'321'600, 39'424'000)
    //   out  : [39'424'000, 52'531'200)   (embp ALIASES the first 1.4M floats
    //                                      of out — dead before gru writes out)
    //   hT   : [52'531'200, 52'563'968)
    //   Wt   : [52'563'968, 52'576'256)   (384 x 32)
    //   Wkt  : [52'576'256, 52'584'448)   (64 x 128)
    float* xpf  = ws;
    float* xpb  = ws + 19660800;
    float* mask = ws + 39321600;
    float* out  = ws + 39424000;
    float* embp = out;                     // alias: used only before gru
    float* hT   = ws + 52531200;
    float* Wt   = ws + 52563968;
    float* Wkt  = ws + 52576256;

    pad_emb_kernel<<<2048, 256, 0, stream>>>(emb, embp);
    prep_w_kernel<<<1, 512, 0, stream>>>(W_f, b_f, W_b, b_b, W_k, Wt, Wkt);
    emb_xproj_kernel<<<1600, 64, 0, stream>>>(ids, embp, Wt, xpf, xpb, mask);
    gru_kernel<<<1024, 64, 0, stream>>>(xpf, xpb, mask, U_f, b_f, U_b, b_b,
                                        out, hT);
    attn_kernel<<<BATCH, 256, 0, stream>>>(out, mask, hT, Wkt, b_k,
                                           W_q, b_q, W_e, b_e, (float*)d_out);
}

// Round 6
// 637.845 us; speedup vs baseline: 1.1419x; 1.1188x over previous
//
#include <hip/hip_runtime.h>
#include <math.h>

#define BATCH 512
#define SEQ   200
#define TOK   10
#define EMB   25
#define HID   64
#define G3    192   // 3*HID
#define CH    20    // gru xp-staging chunk (SEQ % CH == 0)
#define NC    (SEQ / CH)

__device__ __forceinline__ float fast_sigmoid(float t) {
    float e = __expf(-t);
    return __builtin_amdgcn_rcpf(1.f + e);
}
__device__ __forceinline__ float fast_tanh(float t) {
    float e2 = __expf(2.f * t);
    return 1.f - 2.f * __builtin_amdgcn_rcpf(e2 + 1.f);
}

typedef const __attribute__((address_space(1))) unsigned int* as1_u32p;
typedef __attribute__((address_space(3))) unsigned int* as3_u32p;

// async global->LDS, 16B/lane. lds base must be wave-uniform; HW adds lane*16.
__device__ __forceinline__ void gload_lds16(const float* g, float* lds_uniform) {
#if __has_builtin(__builtin_amdgcn_global_load_lds)
    __builtin_amdgcn_global_load_lds((as1_u32p)g, (as3_u32p)lds_uniform, 16, 0, 0);
#else
    ((float4*)lds_uniform)[threadIdx.x & 63] = *(const float4*)g;
#endif
}

// ---------------------------------------------------------------------------
// Prep: Wkt[64][128] = transposed W_k (row j = W_k column j).
// ---------------------------------------------------------------------------
__global__ __launch_bounds__(512) void prep_w_kernel(
    const float* __restrict__ W_k, float* __restrict__ Wkt)
{
    for (int i = threadIdx.x; i < 2 * HID * HID; i += 512) {
        int r = i >> 7, col = i & 127;
        Wkt[i] = W_k[col * HID + r];     // Wkt[r][col] = W_k[col][r]
    }
}

// ---------------------------------------------------------------------------
// Kernel 1 v4: fused embedding-bag mean + input projection.
// ONE WAVE PER POSITION (grid-stride). Gathers coalesced (lanes 0..24 read
// one 100-B emb row). Lane l holds 6 weight columns {l,64+l,128+l} of W_f
// and W_b = 150 floats in registers. amdgpu_waves_per_eu(1,1) pins the
// allocator to 1 wave/SIMD -> full 512-VGPR budget -> the weight arrays
// STAY RESIDENT (R3/R4/R5 all sank them with launch_bounds alone).
// ---------------------------------------------------------------------------
__global__ __attribute__((amdgpu_flat_work_group_size(64, 64),
                          amdgpu_waves_per_eu(1, 1)))
void emb_xproj_kernel(
    const int* __restrict__ ids_g, const float* __restrict__ emb,
    const float* __restrict__ W_f, const float* __restrict__ b_f,
    const float* __restrict__ W_b, const float* __restrict__ b_b,
    float* __restrict__ xpf, float* __restrict__ xpb, float* __restrict__ mask)
{
    const int lane = threadIdx.x;

    float Wr[6][EMB];
    float bl[6];
    #pragma unroll
    for (int g = 0; g < 3; g++) {
        #pragma unroll
        for (int e = 0; e < EMB; e++) {
            Wr[g][e]     = W_f[e * G3 + g * 64 + lane];
            Wr[g + 3][e] = W_b[e * G3 + g * 64 + lane];
        }
        bl[g]     = b_f[g * 64 + lane];
        bl[g + 3] = b_b[g * 64 + lane];
    }

    for (int pos = blockIdx.x; pos < BATCH * SEQ; pos += gridDim.x) {
        const int* ids = ids_g + (size_t)pos * TOK;
        float acc = 0.f;
        int cnt = 0;
        int id0 = ids[0];
        #pragma unroll
        for (int t = 0; t < TOK; t++) {
            int id = ids[t];
            if (id != 0) {
                cnt++;
                if (lane < EMB) acc += emb[(size_t)id * EMB + lane];
            }
        }
        if (lane == 0) mask[pos] = (id0 != 0) ? 1.f : 0.f;
        float xv = cnt ? acc / (float)cnt : 0.f;

        float xr[EMB];
        #pragma unroll
        for (int e = 0; e < EMB; e++) xr[e] = __shfl(xv, e);

        float* const of = xpf + (size_t)pos * G3;
        float* const ob = xpb + (size_t)pos * G3;
        #pragma unroll
        for (int g = 0; g < 6; g++) {
            float a0 = bl[g], a1 = 0.f;
            #pragma unroll
            for (int e = 0; e < 24; e += 2) {
                a0 = fmaf(xr[e + 0], Wr[g][e + 0], a0);
                a1 = fmaf(xr[e + 1], Wr[g][e + 1], a1);
            }
            a0 = fmaf(xr[24], Wr[g][24], a0);
            float v = a0 + a1;
            if (g < 3) of[g * 64 + lane] = v;
            else       ob[(g - 3) * 64 + lane] = v;
        }
    }
}

// ---------------------------------------------------------------------------
// Kernel 2 v6: GRU scan — one wave per (batch, direction).
// Uz/Ur/Uh per-lane registers (192). xp staged per CH=20 steps via async
// global_load_lds (zero VGPR cost). amdgpu_waves_per_eu(1,1) -> full VGPR
// budget, no AGPR shuffling (R2's hidden 2x cost). No barriers in the loop.
// ---------------------------------------------------------------------------
__global__ __attribute__((amdgpu_flat_work_group_size(64, 64),
                          amdgpu_waves_per_eu(1, 1)))
void gru_kernel(
    const float* __restrict__ xpf, const float* __restrict__ xpb,
    const float* __restrict__ maskg,
    const float* __restrict__ U_f, const float* __restrict__ b_f,
    const float* __restrict__ U_b, const float* __restrict__ b_b,
    float* __restrict__ outg, float* __restrict__ hT)
{
    const int bidx = blockIdx.x;
    const int dir  = bidx >> 9;
    const int b    = bidx & 511;
    const int j    = threadIdx.x;

    const float* U    = dir ? U_b : U_f;
    const float* bias = dir ? b_b : b_f;
    const float* xp_d = (dir ? xpb : xpf) + (size_t)b * SEQ * G3;

    float Uz[HID], Ur[HID], Uh[HID];
    #pragma unroll
    for (int k = 0; k < HID; k++) {
        Uz[k] = U[k * G3 + j];
        Ur[k] = U[k * G3 + HID + j];
        Uh[k] = U[k * G3 + 2 * HID + j];
    }
    const float bzr = bias[G3 + j];
    const float brr = bias[G3 + HID + j];
    const float bhr = bias[G3 + 2 * HID + j];

    __shared__ float ms[SEQ];
    __shared__ __align__(16) float hs[HID];
    __shared__ __align__(16) float xs[2][CH * G3];   // 2 x 15 KB

    for (int i = j; i < SEQ; i += 64) ms[i] = maskg[(size_t)b * SEQ + i];
    hs[j] = 0.f;
    __syncthreads();

    {
        const int r0 = dir ? (SEQ - CH) : 0;
        const float* src = xp_d + (size_t)r0 * G3;
        #pragma unroll
        for (int w = 0; w < 15; w++)
            gload_lds16(src + w * 256 + j * 4, &xs[0][w * 256]);
    }

    float h = 0.f;
    float* obase = outg + (size_t)b * SEQ * (2 * HID) + dir * HID + j;
    const float4* hs4 = (const float4*)hs;

    for (int c = 0; c < NC; c++) {
        __builtin_amdgcn_s_waitcnt(0x0f70);   // vmcnt(0): chunk data landed
        __builtin_amdgcn_wave_barrier();
        if (c + 1 < NC) {                     // prefetch next chunk (async)
            const int t0 = (c + 1) * CH;
            const int r0 = dir ? (SEQ - t0 - CH) : t0;
            const float* src = xp_d + (size_t)r0 * G3;
            float* dstb = xs[(c + 1) & 1];
            #pragma unroll
            for (int w = 0; w < 15; w++)
                gload_lds16(src + w * 256 + j * 4, &dstb[w * 256]);
        }

        const float* xbuf = xs[c & 1];
        for (int i = 0; i < CH; i++) {
            const int t  = c * CH + i;
            const int s  = dir ? (SEQ - 1 - t) : t;
            const int li = dir ? (CH - 1 - i) : i;
            const float* xr = xbuf + li * G3 + j;
            const float cz = xr[0], cr = xr[64], chv = xr[128];

            float az0 = bzr, az1 = 0.f, ar0 = brr, ar1 = 0.f, ah0 = bhr, ah1 = 0.f;
            #pragma unroll
            for (int k4 = 0; k4 < HID / 4; k4++) {
                float4 hv = hs4[k4];
                int k = k4 * 4;
                az0 = fmaf(hv.x, Uz[k],     az0); az1 = fmaf(hv.y, Uz[k + 1], az1);
                az0 = fmaf(hv.z, Uz[k + 2], az0); az1 = fmaf(hv.w, Uz[k + 3], az1);
                ar0 = fmaf(hv.x, Ur[k],     ar0); ar1 = fmaf(hv.y, Ur[k + 1], ar1);
                ar0 = fmaf(hv.z, Ur[k + 2], ar0); ar1 = fmaf(hv.w, Ur[k + 3], ar1);
                ah0 = fmaf(hv.x, Uh[k],     ah0); ah1 = fmaf(hv.y, Uh[k + 1], ah1);
                ah0 = fmaf(hv.z, Uh[k + 2], ah0); ah1 = fmaf(hv.w, Uh[k + 3], ah1);
            }

            float z  = fast_sigmoid(cz + az0 + az1);
            float r  = fast_sigmoid(cr + ar0 + ar1);
            float hh = fast_tanh(chv + r * (ah0 + ah1));
            float hn = z * h + (1.f - z) * hh;
            hn = (ms[s] != 0.f) ? hn : h;
            h = hn;

            __builtin_amdgcn_wave_barrier();
            hs[j] = hn;
            __builtin_amdgcn_wave_barrier();

            obase[(size_t)s * (2 * HID)] = hn;   // fire-and-forget
        }
    }
    if (dir == 0) hT[(size_t)b * HID + j] = h;
}

// ---------------------------------------------------------------------------
// Kernel 3 v4: attention. One block (256 thr) per batch. Score phase is
// POSITION-PER-LANE: lane tid holds out-row (32 float4 regs, waves_per_eu
// (2,2) -> 256-VGPR budget, resident); W_k columns come from LDS as
// lane-UNIFORM b128 broadcasts (cheap; replaces R1-R4's 25600 per-lane
// ds_read_b32 per block, ~120us device-wide).
// ---------------------------------------------------------------------------
__global__ __attribute__((amdgpu_flat_work_group_size(256, 256),
                          amdgpu_waves_per_eu(2, 2)))
void attn_kernel(
    const float* __restrict__ outg, const float* __restrict__ maskg,
    const float* __restrict__ hT, const float* __restrict__ Wkt,
    const float* __restrict__ b_k, const float* __restrict__ W_q,
    const float* __restrict__ b_q, const float* __restrict__ W_e,
    const float* __restrict__ b_e, float* __restrict__ ctx)
{
    const int b   = blockIdx.x;
    const int tid = threadIdx.x;

    __shared__ __align__(16) float Wks[2 * HID * HID];   // 32 KB, row j = col j of W_k
    __shared__ float qs[HID];
    __shared__ float bks[HID];
    __shared__ float wes[HID];
    __shared__ float es[SEQ];
    __shared__ float part[2 * HID];

    {   // stage Wkt (already transposed) + small vectors
        const float4* src = (const float4*)Wkt;
        float4* dst = (float4*)Wks;
        #pragma unroll
        for (int q = 0; q < 8; q++) dst[q * 256 + tid] = src[q * 256 + tid];
        if (tid < HID) {
            bks[tid] = b_k[tid];
            wes[tid] = W_e[tid];
            float q = b_q[tid];
            const float* hrow = hT + (size_t)b * HID;
            #pragma unroll 8
            for (int i = 0; i < HID; i++) q = fmaf(hrow[i], W_q[i * HID + tid], q);
            qs[tid] = q;
        }
    }
    __syncthreads();

    // ---- scores: lane tid owns sequence position s = tid (s < 200) ----
    if (tid < SEQ) {
        const float4* orow = (const float4*)(outg + ((size_t)b * SEQ + tid) * (2 * HID));
        float4 o[32];
        #pragma unroll
        for (int q = 0; q < 32; q++) o[q] = orow[q];

        float e_acc = 0.f;
        for (int j = 0; j < HID; j++) {
            const float4* wc = (const float4*)(Wks + j * 128);   // uniform addr
            float k0 = bks[j], k1 = 0.f, k2 = 0.f, k3 = 0.f;
            #pragma unroll
            for (int q = 0; q < 32; q += 4) {
                float4 w0 = wc[q], w1 = wc[q + 1], w2 = wc[q + 2], w3 = wc[q + 3];
                k0 = fmaf(o[q].x,     w0.x, k0); k0 = fmaf(o[q].y,     w0.y, k0);
                k0 = fmaf(o[q].z,     w0.z, k0); k0 = fmaf(o[q].w,     w0.w, k0);
                k1 = fmaf(o[q + 1].x, w1.x, k1); k1 = fmaf(o[q + 1].y, w1.y, k1);
                k1 = fmaf(o[q + 1].z, w1.z, k1); k1 = fmaf(o[q + 1].w, w1.w, k1);
                k2 = fmaf(o[q + 2].x, w2.x, k2); k2 = fmaf(o[q + 2].y, w2.y, k2);
                k2 = fmaf(o[q + 2].z, w2.z, k2); k2 = fmaf(o[q + 2].w, w2.w, k2);
                k3 = fmaf(o[q + 3].x, w3.x, k3); k3 = fmaf(o[q + 3].y, w3.y, k3);
                k3 = fmaf(o[q + 3].z, w3.z, k3); k3 = fmaf(o[q + 3].w, w3.w, k3);
            }
            float k = (k0 + k1) + (k2 + k3);
            e_acc = fmaf(wes[j], fast_tanh(k + qs[j]), e_acc);
        }
        float pen = (maskg[(size_t)b * SEQ + tid] != 0.f) ? 0.f : -1e9f;
        es[tid] = e_acc + b_e[0] + pen;
    }
    __syncthreads();

    // ---- softmax over 200 scores (single wave) ----
    if (tid < 64) {
        float mx = -1e30f;
        for (int s2 = tid; s2 < SEQ; s2 += 64) mx = fmaxf(mx, es[s2]);
        #pragma unroll
        for (int off = 32; off > 0; off >>= 1) mx = fmaxf(mx, __shfl_xor(mx, off));
        float sum = 0.f;
        for (int s2 = tid; s2 < SEQ; s2 += 64) {
            float w = expf(es[s2] - mx);
            es[s2] = w;
            sum += w;
        }
        #pragma unroll
        for (int off = 32; off > 0; off >>= 1) sum += __shfl_xor(sum, off);
        float inv = 1.f / sum;
        for (int s2 = tid; s2 < SEQ; s2 += 64) es[s2] *= inv;
    }
    __syncthreads();

    // ---- context: coalesced global reread ----
    {
        const int half = tid >> 7;
        const int jj   = tid & 127;
        float a = 0.f;
        for (int s2 = half; s2 < SEQ; s2 += 2)
            a = fmaf(es[s2], outg[((size_t)b * SEQ + s2) * (2 * HID) + jj], a);
        if (half == 1) part[jj] = a;
        __syncthreads();
        if (half == 0)
            ctx[(size_t)b * (2 * HID) + jj] = a + part[jj];
    }
}

// ---------------------------------------------------------------------------
extern "C" void kernel_launch(void* const* d_in, const int* in_sizes, int n_in,
                              void* d_out, int out_size, void* d_ws, size_t ws_size,
                              hipStream_t stream) {
    const int*   ids = (const int*)  d_in[0];
    const float* emb = (const float*)d_in[1];
    const float* W_f = (const float*)d_in[2];
    const float* U_f = (const float*)d_in[3];
    const float* b_f = (const float*)d_in[4];
    const float* W_b = (const float*)d_in[5];
    const float* U_b = (const float*)d_in[6];
    const float* b_b = (const float*)d_in[7];
    const float* W_k = (const float*)d_in[8];
    const float* b_k = (const float*)d_in[9];
    const float* W_q = (const float*)d_in[10];
    const float* b_q = (const float*)d_in[11];
    const float* W_e = (const float*)d_in[12];
    const float* b_e = (const float*)d_in[13];

    float* ws = (float*)d_ws;
    // workspace layout (floats):
    //   xpf  : [0, 19'660'800)
    //   xpb  : [19'660'800, 39'321'600)
    //   mask : [39'321'600, 39'424'000)
    //   out  : [39'424'000, 52'531'200)
    //   hT   : [52'531'200, 52'563'968)
    //   Wkt  : [52'563'968, 52'572'160)   (64 x 128)
    float* xpf  = ws;
    float* xpb  = ws + 19660800;
    float* mask = ws + 39321600;
    float* out  = ws + 39424000;
    float* hT   = ws + 52531200;
    float* Wkt  = ws + 52563968;

    prep_w_kernel<<<1, 512, 0, stream>>>(W_k, Wkt);
    emb_xproj_kernel<<<4096, 64, 0, stream>>>(ids, emb, W_f, b_f, W_b, b_b,
                                              xpf, xpb, mask);
    gru_kernel<<<1024, 64, 0, stream>>>(xpf, xpb, mask, U_f, b_f, U_b, b_b,
                                        out, hT);
    attn_kernel<<<BATCH, 256, 0, stream>>>(out, mask, hT, Wkt, b_k,
                                           W_q, b_q, W_e, b_e, (float*)d_out);
}

// Round 7
// 469.522 us; speedup vs baseline: 1.5513x; 1.3585x over previous
//
#include <hip/hip_runtime.h>
#include <math.h>

#define BATCH 512
#define SEQ   200
#define TOK   10
#define EMB   25
#define HID   64
#define G3    192   // 3*HID
#define CH    20    // gru xp-staging chunk (SEQ % CH == 0)
#define NC    (SEQ / CH)
#define NPOS  (BATCH * SEQ)   // 102400

__device__ __forceinline__ float fast_sigmoid(float t) {
    float e = __expf(-t);
    return __builtin_amdgcn_rcpf(1.f + e);
}
__device__ __forceinline__ float fast_tanh(float t) {
    float e2 = __expf(2.f * t);
    return 1.f - 2.f * __builtin_amdgcn_rcpf(e2 + 1.f);
}

typedef const __attribute__((address_space(1))) unsigned int* as1_u32p;
typedef __attribute__((address_space(3))) unsigned int* as3_u32p;

// async global->LDS, 16B/lane. lds base wave-uniform; HW adds lane*16.
__device__ __forceinline__ void gload_lds16(const float* g, float* lds_uniform) {
#if __has_builtin(__builtin_amdgcn_global_load_lds)
    __builtin_amdgcn_global_load_lds((as1_u32p)g, (as3_u32p)lds_uniform, 16, 0, 0);
#else
    ((float4*)lds_uniform)[threadIdx.x & 63] = *(const float4*)g;
#endif
}

// ---------------------------------------------------------------------------
// Kernel 1: masked-mean embedding bag + step mask (R1 design, proven).
// One 32-lane group per (b,s); lanes 0..24 handle the 25 embedding dims.
// ---------------------------------------------------------------------------
__global__ __launch_bounds__(256) void emb_mean_kernel(
    const int* __restrict__ ids_g, const float* __restrict__ emb,
    float* __restrict__ x, float* __restrict__ mask)
{
    int grp  = blockIdx.x * 8 + (threadIdx.x >> 5);
    int lane = threadIdx.x & 31;
    if (grp >= NPOS) return;
    const int* ids = ids_g + (size_t)grp * TOK;
    float acc = 0.f;
    int cnt = 0;
    #pragma unroll
    for (int t = 0; t < TOK; t++) {
        int id = ids[t];
        if (id != 0) {
            cnt++;
            if (lane < EMB) acc += emb[(size_t)id * EMB + lane];
        }
    }
    if (lane < EMB)
        x[(size_t)grp * EMB + lane] = cnt ? acc / (float)cnt : 0.f;
    if (lane == 0)
        mask[grp] = (ids[0] != 0) ? 1.f : 0.f;
}

// ---------------------------------------------------------------------------
// Kernel 2: input projection as a tiled GEMM. C[102400 x 384] = x[.,25] @ W.
// Block tile 64 pos x 64 cols; 256 threads, 4x4 register tile each (no big
// per-lane arrays -> nothing for the allocator to sink; this is the fix for
// R3-R6's 280-380us weight-reload disaster). grid = (1600 M-tiles, 6 N-tiles);
// N-tiles 0..2 -> W_f cols -> xpf, 3..5 -> W_b cols -> xpb.
// ---------------------------------------------------------------------------
__global__ __launch_bounds__(256) void xproj_gemm_kernel(
    const float* __restrict__ x,
    const float* __restrict__ W_f, const float* __restrict__ b_f,
    const float* __restrict__ W_b, const float* __restrict__ b_b,
    float* __restrict__ xpf, float* __restrict__ xpb)
{
    const int tid = threadIdx.x;
    const int tx = tid & 15, ty = tid >> 4;
    const int m0 = ty * 4, n0 = tx * 4;
    const int pos0 = blockIdx.x * 64;
    const int nt   = blockIdx.y;          // 0..5

    __shared__ float xst[EMB * 68];       // [k][m] transposed, pad 68
    __shared__ float wn[EMB * 64];        // [k][n]
    __shared__ float bns[64];

    const float* Wsrc = (nt < 3) ? W_f : W_b;
    const float* bsrc = (nt < 3) ? b_f : b_b;
    const int c0 = (nt % 3) * 64;

    {   // stage x tile (coalesced linear read, transposed store)
        const float* xlin = x + (size_t)pos0 * EMB;
        for (int i = tid; i < 64 * EMB; i += 256) {
            int m = i / EMB, k = i - m * EMB;
            xst[k * 68 + m] = xlin[i];
        }
        for (int i = tid; i < EMB * 64; i += 256) {
            int e = i >> 6, n = i & 63;
            wn[i] = Wsrc[e * G3 + c0 + n];
        }
        if (tid < 64) bns[tid] = bsrc[c0 + tid];
    }
    __syncthreads();

    float acc[4][4];
    #pragma unroll
    for (int i = 0; i < 4; i++) {
        float b0 = bns[n0 + 0], b1 = bns[n0 + 1], b2 = bns[n0 + 2], b3 = bns[n0 + 3];
        acc[i][0] = b0; acc[i][1] = b1; acc[i][2] = b2; acc[i][3] = b3;
    }

    #pragma unroll
    for (int k = 0; k < EMB; k++) {
        float4 av = *(const float4*)&xst[k * 68 + m0];
        float4 bv = *(const float4*)&wn[k * 64 + n0];
        acc[0][0] = fmaf(av.x, bv.x, acc[0][0]); acc[0][1] = fmaf(av.x, bv.y, acc[0][1]);
        acc[0][2] = fmaf(av.x, bv.z, acc[0][2]); acc[0][3] = fmaf(av.x, bv.w, acc[0][3]);
        acc[1][0] = fmaf(av.y, bv.x, acc[1][0]); acc[1][1] = fmaf(av.y, bv.y, acc[1][1]);
        acc[1][2] = fmaf(av.y, bv.z, acc[1][2]); acc[1][3] = fmaf(av.y, bv.w, acc[1][3]);
        acc[2][0] = fmaf(av.z, bv.x, acc[2][0]); acc[2][1] = fmaf(av.z, bv.y, acc[2][1]);
        acc[2][2] = fmaf(av.z, bv.z, acc[2][2]); acc[2][3] = fmaf(av.z, bv.w, acc[2][3]);
        acc[3][0] = fmaf(av.w, bv.x, acc[3][0]); acc[3][1] = fmaf(av.w, bv.y, acc[3][1]);
        acc[3][2] = fmaf(av.w, bv.z, acc[3][2]); acc[3][3] = fmaf(av.w, bv.w, acc[3][3]);
    }

    float* dstbase = (nt < 3) ? (xpf + (size_t)pos0 * G3 + nt * 64)
                              : (xpb + (size_t)pos0 * G3 + (nt - 3) * 64);
    #pragma unroll
    for (int i = 0; i < 4; i++)
        *(float4*)(dstbase + (size_t)(m0 + i) * G3 + n0) =
            make_float4(acc[i][0], acc[i][1], acc[i][2], acc[i][3]);
}

// ---------------------------------------------------------------------------
// Kernel 3: GRU scan — one wave per (batch, direction). h NEVER leaves
// registers: broadcast via v_readlane (no LDS round-trip, no fences on the
// h-dependence chain). xp staged per CH=20 steps via async global_load_lds.
// Per-step chain: 64 readlane + 192 FMA + activations (~480 cy).
// ---------------------------------------------------------------------------
__global__ __launch_bounds__(64, 1) void gru_kernel(
    const float* __restrict__ xpf, const float* __restrict__ xpb,
    const float* __restrict__ maskg,
    const float* __restrict__ U_f, const float* __restrict__ b_f,
    const float* __restrict__ U_b, const float* __restrict__ b_b,
    float* __restrict__ outg, float* __restrict__ hT)
{
    const int bidx = blockIdx.x;
    const int dir  = bidx >> 9;
    const int b    = bidx & 511;
    const int j    = threadIdx.x;

    const float* U    = dir ? U_b : U_f;
    const float* bias = dir ? b_b : b_f;
    const float* xp_d = (dir ? xpb : xpf) + (size_t)b * SEQ * G3;

    float Uz[HID], Ur[HID], Uh[HID];
    #pragma unroll
    for (int k = 0; k < HID; k++) {
        Uz[k] = U[k * G3 + j];
        Ur[k] = U[k * G3 + HID + j];
        Uh[k] = U[k * G3 + 2 * HID + j];
    }
    const float bzr = bias[G3 + j];
    const float brr = bias[G3 + HID + j];
    const float bhr = bias[G3 + 2 * HID + j];

    __shared__ float ms[SEQ];
    __shared__ __align__(16) float xs[2][CH * G3];   // 2 x 15 KB

    for (int i = j; i < SEQ; i += 64) ms[i] = maskg[(size_t)b * SEQ + i];
    __syncthreads();

    {   // chunk-0 staging
        const int r0 = dir ? (SEQ - CH) : 0;
        const float* src = xp_d + (size_t)r0 * G3;
        #pragma unroll
        for (int w = 0; w < 15; w++)
            gload_lds16(src + w * 256 + j * 4, &xs[0][w * 256]);
    }

    float h = 0.f;
    float* obase = outg + (size_t)b * SEQ * (2 * HID) + dir * HID + j;

    for (int c = 0; c < NC; c++) {
        __builtin_amdgcn_s_waitcnt(0x0f70);   // vmcnt(0): chunk landed
        __builtin_amdgcn_wave_barrier();
        if (c + 1 < NC) {                     // async prefetch next chunk
            const int t0 = (c + 1) * CH;
            const int r0 = dir ? (SEQ - t0 - CH) : t0;
            const float* src = xp_d + (size_t)r0 * G3;
            float* dstb = xs[(c + 1) & 1];
            #pragma unroll
            for (int w = 0; w < 15; w++)
                gload_lds16(src + w * 256 + j * 4, &dstb[w * 256]);
        }

        const float* xbuf = xs[c & 1];
        for (int i = 0; i < CH; i++) {
            const int t  = c * CH + i;
            const int s  = dir ? (SEQ - 1 - t) : t;
            const int li = dir ? (CH - 1 - i) : i;
            const float* xr = xbuf + li * G3 + j;
            const float cz = xr[0], cr = xr[64], chv = xr[128];

            const int hb = __float_as_int(h);
            float az0 = bzr, az1 = 0.f, ar0 = brr, ar1 = 0.f, ah0 = bhr, ah1 = 0.f;
            #pragma unroll
            for (int k = 0; k < HID; k += 2) {
                float h0 = __int_as_float(__builtin_amdgcn_readlane(hb, k));
                float h1 = __int_as_float(__builtin_amdgcn_readlane(hb, k + 1));
                az0 = fmaf(h0, Uz[k], az0); az1 = fmaf(h1, Uz[k + 1], az1);
                ar0 = fmaf(h0, Ur[k], ar0); ar1 = fmaf(h1, Ur[k + 1], ar1);
                ah0 = fmaf(h0, Uh[k], ah0); ah1 = fmaf(h1, Uh[k + 1], ah1);
            }

            float z  = fast_sigmoid(cz + az0 + az1);
            float r  = fast_sigmoid(cr + ar0 + ar1);
            float hh = fast_tanh(chv + r * (ah0 + ah1));
            float hn = z * h + (1.f - z) * hh;
            hn = (ms[s] != 0.f) ? hn : h;
            h = hn;

            obase[(size_t)s * (2 * HID)] = hn;   // fire-and-forget
        }
    }
    if (dir == 0) hT[(size_t)b * HID + j] = h;
}

// ---------------------------------------------------------------------------
// Kernel 4: keys GEMM. keys[102400 x 64] = out[.,128] @ W_k[128 x 64] + b_k.
// Same tile template as xproj_gemm: 64x64 tile, K=128, 4x4/thread.
// ---------------------------------------------------------------------------
__global__ __launch_bounds__(256) void keys_gemm_kernel(
    const float* __restrict__ outg, const float* __restrict__ W_k,
    const float* __restrict__ b_k, float* __restrict__ keys)
{
    const int tid = threadIdx.x;
    const int tx = tid & 15, ty = tid >> 4;
    const int m0 = ty * 4, n0 = tx * 4;
    const int pos0 = blockIdx.x * 64;

    __shared__ float outs[64 * 129];      // [m][k] pad 129 (2-way conflicts only)
    __shared__ float wks[128 * 64];       // [k][n] — native W_k layout
    __shared__ float bks[64];

    {
        const float* olin = outg + (size_t)pos0 * (2 * HID);
        for (int i = tid; i < 64 * 128; i += 256) {
            int m = i >> 7, k = i & 127;
            outs[m * 129 + k] = olin[i];
        }
        for (int i = tid; i < 128 * 64; i += 256) wks[i] = W_k[i];
        if (tid < 64) bks[tid] = b_k[tid];
    }
    __syncthreads();

    float acc[4][4];
    #pragma unroll
    for (int i = 0; i < 4; i++) {
        acc[i][0] = bks[n0 + 0]; acc[i][1] = bks[n0 + 1];
        acc[i][2] = bks[n0 + 2]; acc[i][3] = bks[n0 + 3];
    }

    for (int k = 0; k < 128; k++) {
        float a0 = outs[(m0 + 0) * 129 + k];
        float a1 = outs[(m0 + 1) * 129 + k];
        float a2 = outs[(m0 + 2) * 129 + k];
        float a3 = outs[(m0 + 3) * 129 + k];
        float4 bv = *(const float4*)&wks[k * 64 + n0];
        acc[0][0] = fmaf(a0, bv.x, acc[0][0]); acc[0][1] = fmaf(a0, bv.y, acc[0][1]);
        acc[0][2] = fmaf(a0, bv.z, acc[0][2]); acc[0][3] = fmaf(a0, bv.w, acc[0][3]);
        acc[1][0] = fmaf(a1, bv.x, acc[1][0]); acc[1][1] = fmaf(a1, bv.y, acc[1][1]);
        acc[1][2] = fmaf(a1, bv.z, acc[1][2]); acc[1][3] = fmaf(a1, bv.w, acc[1][3]);
        acc[2][0] = fmaf(a2, bv.x, acc[2][0]); acc[2][1] = fmaf(a2, bv.y, acc[2][1]);
        acc[2][2] = fmaf(a2, bv.z, acc[2][2]); acc[2][3] = fmaf(a2, bv.w, acc[2][3]);
        acc[3][0] = fmaf(a3, bv.x, acc[3][0]); acc[3][1] = fmaf(a3, bv.y, acc[3][1]);
        acc[3][2] = fmaf(a3, bv.z, acc[3][2]); acc[3][3] = fmaf(a3, bv.w, acc[3][3]);
    }

    #pragma unroll
    for (int i = 0; i < 4; i++)
        *(float4*)(keys + (size_t)(pos0 + m0 + i) * HID + n0) =
            make_float4(acc[i][0], acc[i][1], acc[i][2], acc[i][3]);
}

// ---------------------------------------------------------------------------
// Kernel 5: attention light. One block (256 thr) per batch: q-proj, per-lane
// tanh score from keys, softmax, context. No weight arrays anywhere.
// ---------------------------------------------------------------------------
__global__ __launch_bounds__(256) void attn_kernel(
    const float* __restrict__ keys, const float* __restrict__ outg,
    const float* __restrict__ maskg, const float* __restrict__ hT,
    const float* __restrict__ W_q, const float* __restrict__ b_q,
    const float* __restrict__ W_e, const float* __restrict__ b_e,
    float* __restrict__ ctx)
{
    const int b   = blockIdx.x;
    const int tid = threadIdx.x;

    __shared__ float qs[HID];
    __shared__ float wes[HID];
    __shared__ float es[SEQ];
    __shared__ float part[2 * HID];

    if (tid < HID) {
        float q = b_q[tid];
        const float* hrow = hT + (size_t)b * HID;
        #pragma unroll 8
        for (int i = 0; i < HID; i++) q = fmaf(hrow[i], W_q[i * HID + tid], q);
        qs[tid] = q;
        wes[tid] = W_e[tid];
    }
    __syncthreads();

    if (tid < SEQ) {
        const float4* kr = (const float4*)(keys + ((size_t)b * SEQ + tid) * HID);
        float e0 = 0.f, e1 = 0.f;
        #pragma unroll
        for (int q4 = 0; q4 < 16; q4++) {
            float4 kv = kr[q4];
            int jj = q4 * 4;
            e0 = fmaf(wes[jj + 0], fast_tanh(kv.x + qs[jj + 0]), e0);
            e1 = fmaf(wes[jj + 1], fast_tanh(kv.y + qs[jj + 1]), e1);
            e0 = fmaf(wes[jj + 2], fast_tanh(kv.z + qs[jj + 2]), e0);
            e1 = fmaf(wes[jj + 3], fast_tanh(kv.w + qs[jj + 3]), e1);
        }
        float pen = (maskg[(size_t)b * SEQ + tid] != 0.f) ? 0.f : -1e9f;
        es[tid] = e0 + e1 + b_e[0] + pen;
    }
    __syncthreads();

    if (tid < 64) {
        float mx = -1e30f;
        for (int s2 = tid; s2 < SEQ; s2 += 64) mx = fmaxf(mx, es[s2]);
        #pragma unroll
        for (int off = 32; off > 0; off >>= 1) mx = fmaxf(mx, __shfl_xor(mx, off));
        float sum = 0.f;
        for (int s2 = tid; s2 < SEQ; s2 += 64) {
            float w = expf(es[s2] - mx);
            es[s2] = w;
            sum += w;
        }
        #pragma unroll
        for (int off = 32; off > 0; off >>= 1) sum += __shfl_xor(sum, off);
        float inv = 1.f / sum;
        for (int s2 = tid; s2 < SEQ; s2 += 64) es[s2] *= inv;
    }
    __syncthreads();

    {
        const int half = tid >> 7;
        const int jj   = tid & 127;
        float a = 0.f;
        for (int s2 = half; s2 < SEQ; s2 += 2)
            a = fmaf(es[s2], outg[((size_t)b * SEQ + s2) * (2 * HID) + jj], a);
        if (half == 1) part[jj] = a;
        __syncthreads();
        if (half == 0)
            ctx[(size_t)b * (2 * HID) + jj] = a + part[jj];
    }
}

// ---------------------------------------------------------------------------
extern "C" void kernel_launch(void* const* d_in, const int* in_sizes, int n_in,
                              void* d_out, int out_size, void* d_ws, size_t ws_size,
                              hipStream_t stream) {
    const int*   ids = (const int*)  d_in[0];
    const float* emb = (const float*)d_in[1];
    const float* W_f = (const float*)d_in[2];
    const float* U_f = (const float*)d_in[3];
    const float* b_f = (const float*)d_in[4];
    const float* W_b = (const float*)d_in[5];
    const float* U_b = (const float*)d_in[6];
    const float* b_b = (const float*)d_in[7];
    const float* W_k = (const float*)d_in[8];
    const float* b_k = (const float*)d_in[9];
    const float* W_q = (const float*)d_in[10];
    const float* b_q = (const float*)d_in[11];
    const float* W_e = (const float*)d_in[12];
    const float* b_e = (const float*)d_in[13];

    float* ws = (float*)d_ws;
    // workspace layout (floats):
    //   xpf  : [0, 19'660'800)            keys ALIASES this (after gru)
    //   xpb  : [19'660'800, 39'321'600)
    //   mask : [39'321'600, 39'424'000)
    //   out  : [39'424'000, 52'531'200)   x ALIASES its head (dead pre-gru)
    //   hT   : [52'531'200, 52'563'968)
    float* xpf  = ws;
    float* xpb  = ws + 19660800;
    float* mask = ws + 39321600;
    float* out  = ws + 39424000;
    float* hT   = ws + 52531200;
    float* x    = out;                     // alias: dead before gru writes out
    float* keys = xpf;                     // alias: written after gru reads xpf

    emb_mean_kernel<<<NPOS / 8, 256, 0, stream>>>(ids, emb, x, mask);
    xproj_gemm_kernel<<<dim3(NPOS / 64, 6), 256, 0, stream>>>(
        x, W_f, b_f, W_b, b_b, xpf, xpb);
    gru_kernel<<<1024, 64, 0, stream>>>(xpf, xpb, mask, U_f, b_f, U_b, b_b,
                                        out, hT);
    keys_gemm_kernel<<<NPOS / 64, 256, 0, stream>>>(out, W_k, b_k, keys);
    attn_kernel<<<BATCH, 256, 0, stream>>>(keys, out, mask, hT,
                                           W_q, b_q, W_e, b_e, (float*)d_out);
}